// Round 1
// baseline (535.009 us; speedup 1.0000x reference)
//
#include <hip/hip_runtime.h>

#define B_   8192
#define T_   406
#define D_   10
#define P_   64
#define K0_  4060          // real K (T*D)
#define KE_  4466          // K0 + T (mask/cp2 extension)
#define KP_  4480          // padded K (35 chunks of 128 bf16)
#define NKS_ 8             // K-split across blocks

// output section offsets (floats), reference return order
#define OUT_SEQ   0
#define OUT_IN    (B_*T_*D_)
#define OUT_DIST  (2*B_*T_*D_)
#define OUT_IDX   (OUT_DIST + B_*P_)
#define OUT_LAB   (OUT_IDX + B_)
#define OUT_MASK  (OUT_LAB + B_)

typedef unsigned short ushort_t;
typedef __attribute__((ext_vector_type(8))) short bf16x8;
typedef __attribute__((ext_vector_type(4))) float f32x4;
typedef __attribute__((address_space(3))) unsigned int lds_uint;
typedef __attribute__((address_space(1))) unsigned int glb_uint;

__device__ __forceinline__ void gl_lds16(const void* g, void* l) {
    // async global->LDS, 16B/lane; LDS dest = wave-uniform base + lane*16
    __builtin_amdgcn_global_load_lds((const glb_uint*)g, (lds_uint*)l, 16, 0, 0);
}
__device__ __forceinline__ ushort_t f2bf(float f) {      // f32 -> bf16 RNE
    unsigned u = __float_as_uint(f);
    return (ushort_t)((u + 0x7fffu + ((u >> 16) & 1u)) >> 16);
}

// ---------------- k1: prototypes -> bf16 B-blob [-2c | cp2 | 0], XOR-swizzled ------
__global__ __launch_bounds__(256) void k1_prep(
    const float* __restrict__ protos, ushort_t* __restrict__ bxb)
{
    const int p = blockIdx.x;
    const int rk = p & 7;
    ushort_t* brow = bxb + (size_t)p * KP_;
    for (int t = threadIdx.x; t < T_; t += 256) {
        const float* src = protos + (size_t)p * K0_ + t * 10;
        float s2 = 0.f;
#pragma unroll
        for (int d = 0; d < 10; d++) {
            float c = src[d];
            s2 += c * c;
            int k = t * 10 + d;
            int ch = k >> 3;
            int sw = (ch & ~7) | ((ch ^ rk) & 7);
            brow[sw * 8 + (k & 7)] = f2bf(-2.f * c);
        }
        int k = K0_ + t;
        int ch = k >> 3;
        int sw = (ch & ~7) | ((ch ^ rk) & 7);
        brow[sw * 8 + (k & 7)] = f2bf(s2);
    }
    for (int k = KE_ + (int)threadIdx.x; k < KP_; k += 256) {
        int ch = k >> 3;
        int sw = (ch & ~7) | ((ch ^ rk) & 7);
        brow[sw * 8 + (k & 7)] = 0;
    }
}

// ---------------- k2: FUSED prep + bf16 MFMA GEMM, BM=128 BN=64 BK=128, K/8 -------
// grid 512: mb = blk>>3 (M tile), ks = blk&7 (K slice: chunks 5,5,5,4,4,4,4,4 of 35)
// A tile is produced in-register from x*mask (bit-identical values to old k0) and
// ds_write'n into the same XOR-swizzled LDS layout; out_in copy is fused into the
// same pass; sq_x partial is folded into `partial` (each slice adds its own share).
__global__ __launch_bounds__(256) void k2_fused(
    const float* __restrict__ x, const float* __restrict__ mask,
    const ushort_t* __restrict__ bxb,
    float* __restrict__ out_in, float* __restrict__ out_mask,
    float* __restrict__ partial)
{
    __shared__ ushort_t As[128 * 128];   // 32KB, rows 256B, swizzled 16B chunks
    __shared__ ushort_t Bs[64 * 128];    // 16KB
    __shared__ float    sqs[128];        // per-tile-row sq_x slice partial
    const int tid = threadIdx.x, wave = tid >> 6, lane = tid & 63;
    const int g = lane >> 4, c = lane & 15;      // staging lane split
    const int mb = blockIdx.x >> 3, ks = blockIdx.x & 7;
    const int rowBase = mb * 128;
    const int cstart = ks * 4 + (ks < 3 ? ks : 3);
    const int ccnt = (ks < 3) ? 5 : 4;
    const int mh = (wave & 1) * 64;      // wave M offset
    const int nh = (wave >> 1) * 32;     // wave N offset
    const int m16 = lane & 15, q4 = lane >> 4;

    // ks==7 blocks own the mask -> out_mask copy (they read full mask rows anyway;
    // this also warms L2 for the extension-region reads below)
    if (ks == 7) {
        for (int r = wave; r < 128; r += 4) {
            const float* mr = mask + (size_t)(rowBase + r) * T_;
            float* omr = out_mask + (size_t)(rowBase + r) * T_;
            for (int j = lane; j < T_; j += 64) omr[j] = mr[j];
        }
    }

    float sqacc[8];
#pragma unroll
    for (int j = 0; j < 8; j++) sqacc[j] = 0.f;
    f32x4 acc[4][2];
#pragma unroll
    for (int a = 0; a < 4; a++)
#pragma unroll
        for (int bb = 0; bb < 2; bb++) acc[a][bb] = (f32x4)0.f;

    for (int cc = 0; cc < ccnt; cc++) {
        const int ch = cstart + cc;
        __syncthreads();                 // previous tile consumed
        // B: wave stages rows [wave*16, wave*16+16) via async DMA (blob pre-swizzled)
#pragma unroll
        for (int j = 0; j < 4; j++) {
            int r = wave * 16 + j * 4 + g;
            const ushort_t* gb = bxb + (size_t)r * KP_ + (ch * 16 + c) * 8;
            gl_lds16(gb, &Bs[(wave * 16 + j * 4) * 128]);
        }
        // A: reg-staged from x*mask; 16 lanes cover one row's 128-float chunk
        const int k8 = ch * 128 + c * 8;
        if (ch < 31) {                   // pure real-k chunks (all of ks 0..6)
#pragma unroll
            for (int j = 0; j < 8; j++) {
                const int r = wave * 32 + j * 4 + g;
                const size_t grow = (size_t)(rowBase + r);
                const float* xr = x + grow * K0_ + k8;
                float4 v0 = *(const float4*)xr;
                float4 v1 = *(const float4*)(xr + 4);
                float4* o = (float4*)(out_in + grow * K0_ + k8);
                o[0] = v0; o[1] = v1;                    // fused input_seq copy
                int t0 = (k8 * 6554) >> 16;              // k8/10 via magic mul
                int bnd = t0 * 10 + 10 - k8;             // elems e<bnd use m0
                float m0 = mask[grow * T_ + t0];
                float m1 = mask[grow * T_ + t0 + 1];     // t0+1 <= 397: in-bounds
                float a0 = v0.x * m0;
                float a1 = v0.y * (1 < bnd ? m0 : m1);
                float a2 = v0.z * (2 < bnd ? m0 : m1);
                float a3 = v0.w * (3 < bnd ? m0 : m1);
                float a4 = v1.x * (4 < bnd ? m0 : m1);
                float a5 = v1.y * (5 < bnd ? m0 : m1);
                float a6 = v1.z * (6 < bnd ? m0 : m1);
                float a7 = v1.w * (7 < bnd ? m0 : m1);
                sqacc[j] += a0 * v0.x + a1 * v0.y + a2 * v0.z + a3 * v0.w
                          + a4 * v1.x + a5 * v1.y + a6 * v1.z + a7 * v1.w;
                bf16x8 w;
                w[0] = (short)f2bf(a0); w[1] = (short)f2bf(a1);
                w[2] = (short)f2bf(a2); w[3] = (short)f2bf(a3);
                w[4] = (short)f2bf(a4); w[5] = (short)f2bf(a5);
                w[6] = (short)f2bf(a6); w[7] = (short)f2bf(a7);
                const int sw = (c & ~7) | ((c ^ (r & 7)) & 7);   // XOR swizzle
                *(bf16x8*)&As[r * 128 + sw * 8] = w;
            }
        } else {                         // ks==7 tail: real | mask-ext | zero pad
#pragma unroll
            for (int j = 0; j < 8; j++) {
                const int r = wave * 32 + j * 4 + g;
                const size_t grow = (size_t)(rowBase + r);
                float av[8];
#pragma unroll
                for (int e = 0; e < 8; e++) {
                    const int k = k8 + e;
                    float a;
                    if (k < K0_) {
                        float xv = x[grow * K0_ + k];
                        int t = (k * 6554) >> 16;
                        float m = mask[grow * T_ + t];
                        a = xv * m;
                        out_in[grow * K0_ + k] = xv;     // tail of the copy
                        sqacc[j] += a * xv;
                    } else if (k < KE_) {
                        a = mask[grow * T_ + (k - K0_)]; // extension: mask value
                    } else {
                        a = 0.f;                         // zero pad
                    }
                    av[e] = a;
                }
                bf16x8 w;
                w[0] = (short)f2bf(av[0]); w[1] = (short)f2bf(av[1]);
                w[2] = (short)f2bf(av[2]); w[3] = (short)f2bf(av[3]);
                w[4] = (short)f2bf(av[4]); w[5] = (short)f2bf(av[5]);
                w[6] = (short)f2bf(av[6]); w[7] = (short)f2bf(av[7]);
                const int sw = (c & ~7) | ((c ^ (r & 7)) & 7);
                *(bf16x8*)&As[r * 128 + sw * 8] = w;
            }
        }
        __syncthreads();                 // staged tile visible (vm+lgkm drained)
#pragma unroll
        for (int k4 = 0; k4 < 4; k4++) {
            const int chk = k4 * 4 + q4;                   // logical 16B chunk
            const int sw = (chk & ~7) | ((chk ^ m16) & 7); // XOR unswizzle
            bf16x8 af[4], bfr[2];
#pragma unroll
            for (int mt = 0; mt < 4; mt++)
                af[mt] = *(const bf16x8*)&As[(mh + mt * 16 + m16) * 128 + sw * 8];
#pragma unroll
            for (int nt = 0; nt < 2; nt++)
                bfr[nt] = *(const bf16x8*)&Bs[(nh + nt * 16 + m16) * 128 + sw * 8];
#pragma unroll
            for (int mt = 0; mt < 4; mt++)
#pragma unroll
                for (int nt = 0; nt < 2; nt++)
                    acc[mt][nt] = __builtin_amdgcn_mfma_f32_16x16x32_bf16(
                        af[mt], bfr[nt], acc[mt][nt], 0, 0, 0);
        }
    }
    // sq_x slice partial: reduce across the 16 lanes of each c-group -> LDS row slot
#pragma unroll
    for (int j = 0; j < 8; j++) {
#pragma unroll
        for (int off = 8; off >= 1; off >>= 1)
            sqacc[j] += __shfl_xor(sqacc[j], off, 64);
        if (c == 0) sqs[wave * 32 + j * 4 + g] = sqacc[j];
    }
    __syncthreads();
    // epilogue: C/D layout col(n)=lane&15, row(m)=(lane>>4)*4+reg  [m89-verified]
    // each slice adds its own sq_x share; sum over ks in k3 reconstructs sq_x[b]
#pragma unroll
    for (int mt = 0; mt < 4; mt++)
#pragma unroll
        for (int nt = 0; nt < 2; nt++)
#pragma unroll
            for (int q = 0; q < 4; q++) {
                int tr = mh + mt * 16 + q4 * 4 + q;
                int gr = rowBase + tr;
                int gp = nh + nt * 16 + m16;
                partial[((size_t)ks * B_ + gr) * P_ + gp] = acc[mt][nt][q] + sqs[tr];
            }
}

// ---------------- k3: reduce partials, argmin, gather, scalars ---------------------
__global__ __launch_bounds__(256) void k3_fin(
    const float* __restrict__ partial, const float* __restrict__ protos,
    const int* __restrict__ label, float* __restrict__ out)
{
    __shared__ int sidx[4];
    const int tid = threadIdx.x, wave = tid >> 6, lane = tid & 63;
    const int b = blockIdx.x * 4 + wave;
    float v = 0.f;
#pragma unroll
    for (int ks = 0; ks < NKS_; ks++)
        v += partial[((size_t)ks * B_ + b) * P_ + lane];
    out[OUT_DIST + (size_t)b * 64 + lane] = v;

    float bv = v; int bi = lane;
#pragma unroll
    for (int off = 32; off >= 1; off >>= 1) {
        float ov = __shfl_xor(bv, off, 64);
        int   oi = __shfl_xor(bi, off, 64);
        if (ov < bv || (ov == bv && oi < bi)) { bv = ov; bi = oi; }
    }
    if (lane == 0) {
        sidx[wave] = bi;
        out[OUT_IDX + b] = (float)bi;
        out[OUT_LAB + b] = (float)label[b];
    }
    __syncthreads();
#pragma unroll
    for (int w2 = 0; w2 < 4; w2++) {
        const int bb = blockIdx.x * 4 + w2;
        const float* src = protos + (size_t)sidx[w2] * (T_ * D_);
        float* dst = out + OUT_SEQ + (size_t)bb * (T_ * D_);
        for (int i = tid; i < 1015; i += 256)
            *(float4*)(dst + 4 * i) = *(const float4*)(src + 4 * i);
    }
}

extern "C" void kernel_launch(void* const* d_in, const int* in_sizes, int n_in,
                              void* d_out, int out_size, void* d_ws, size_t ws_size,
                              hipStream_t stream) {
    const float* x      = (const float*)d_in[0];
    const int*   label  = (const int*)d_in[1];
    const float* mask   = (const float*)d_in[2];
    const float* protos = (const float*)d_in[3];
    float* out = (float*)d_out;
    char*  ws  = (char*)d_ws;

    ushort_t* bxb     = (ushort_t*)(ws);            // 64*4480*2 = 573,440 B
    float*    partial = (float*)(ws + 573440);      // 8*8192*64*4 = 16.8 MB
    // total ws use 17.35 MB (<= previous layout's 17.38 MB)

    hipLaunchKernelGGL(k1_prep, dim3(64), dim3(256), 0, stream, protos, bxb);
    hipLaunchKernelGGL(k2_fused, dim3(512), dim3(256), 0, stream,
                       x, mask, bxb, out + OUT_IN, out + OUT_MASK, partial);
    hipLaunchKernelGGL(k3_fin, dim3(B_ / 4), dim3(256), 0, stream,
                       partial, protos, label, out);
}

// Round 2
// 446.939 us; speedup vs baseline: 1.1970x; 1.1970x over previous
//
#include <hip/hip_runtime.h>

#define B_   8192
#define T_   406
#define D_   10
#define P_   64
#define K0_  4060          // real K (T*D)
#define KE_  4466          // K0 + T (mask/cp2 extension)
#define KP_  4480          // padded K (35 chunks of 128 bf16)
#define NKS_ 8             // K-split across blocks

// output section offsets (floats), reference return order
#define OUT_SEQ   0
#define OUT_IN    (B_*T_*D_)
#define OUT_DIST  (2*B_*T_*D_)
#define OUT_IDX   (OUT_DIST + B_*P_)
#define OUT_LAB   (OUT_IDX + B_)
#define OUT_MASK  (OUT_LAB + B_)

typedef unsigned short ushort_t;
typedef __attribute__((ext_vector_type(8))) short bf16x8;
typedef __attribute__((ext_vector_type(4))) float f32x4;
typedef __attribute__((address_space(3))) unsigned int lds_uint;
typedef __attribute__((address_space(1))) unsigned int glb_uint;

__device__ __forceinline__ void gl_lds16(const void* g, void* l) {
    // async global->LDS, 16B/lane; LDS dest = wave-uniform base + lane*16
    __builtin_amdgcn_global_load_lds((const glb_uint*)g, (lds_uint*)l, 16, 0, 0);
}
__device__ __forceinline__ ushort_t f2bf(float f) {      // f32 -> bf16 RNE
    unsigned u = __float_as_uint(f);
    return (ushort_t)((u + 0x7fffu + ((u >> 16) & 1u)) >> 16);
}

// ---------------- k0: stream x/mask once -> out_in, out_mask, sq_x, bf16 A-blob ----
// blocks [0,2048): A-path (4 rows/block). blocks [2048,2112): B-blob (former k1) —
// merged so the independent prototype prep overlaps the x stream instead of
// serializing after it.
// axb[row][k'] bf16, rows 8960B; 16B-chunk c stored at position (c&~7)|((c^row)&7)
__global__ __launch_bounds__(256) void k0_prep(
    const float* __restrict__ x, const float* __restrict__ mask,
    const float* __restrict__ protos,
    ushort_t* __restrict__ axb, ushort_t* __restrict__ bxb,
    float* __restrict__ out_in, float* __restrict__ out_mask,
    float* __restrict__ sq_x)
{
    __shared__ float ms[4][416];
    if (blockIdx.x >= 2048) {            // ---- B-blob role (former k1) ----
        const int p = blockIdx.x - 2048;
        const int rk = p & 7;
        ushort_t* brow = bxb + (size_t)p * KP_;
        for (int t = threadIdx.x; t < T_; t += 256) {
            const float* src = protos + (size_t)p * K0_ + t * 10;
            float s2 = 0.f;
#pragma unroll
            for (int d = 0; d < 10; d++) {
                float c = src[d];
                s2 += c * c;
                int k = t * 10 + d;
                int ch = k >> 3;
                int sw = (ch & ~7) | ((ch ^ rk) & 7);
                brow[sw * 8 + (k & 7)] = f2bf(-2.f * c);
            }
            int k = K0_ + t;
            int ch = k >> 3;
            int sw = (ch & ~7) | ((ch ^ rk) & 7);
            brow[sw * 8 + (k & 7)] = f2bf(s2);
        }
        for (int k = KE_ + (int)threadIdx.x; k < KP_; k += 256) {
            int ch = k >> 3;
            int sw = (ch & ~7) | ((ch ^ rk) & 7);
            brow[sw * 8 + (k & 7)] = 0;
        }
        return;
    }
    // ---- A-path: stream x once, fused out_in/out_mask copies, sq_x, bf16 blob ----
    const int wave = threadIdx.x >> 6, lane = threadIdx.x & 63;
    const int row = blockIdx.x * 4 + wave;
    const float* mrow = mask + (size_t)row * T_;
    float* omrow = out_mask + (size_t)row * T_;
    for (int j = lane; j < T_; j += 64) { float m = mrow[j]; ms[wave][j] = m; omrow[j] = m; }
    // same-wave LDS RAW: compiler orders via lgkmcnt, no barrier needed
    const float4* x4 = (const float4*)(x + (size_t)row * K0_);
    float4* o4 = (float4*)(out_in + (size_t)row * K0_);
    ushort_t* arow = axb + (size_t)row * KP_;
    const int rk = row & 7;
    float sx = 0.f;
    for (int i = lane; i < 1015; i += 64) {
        float4 v = x4[i];
        o4[i] = v;                                        // fused input_seq copy
        int k = 4 * i;
        int t0 = (k*6554)>>16, t1 = ((k+1)*6554)>>16;
        int t2 = ((k+2)*6554)>>16, t3 = ((k+3)*6554)>>16; // k/10 via magic mul
        float a0 = v.x * ms[wave][t0], a1 = v.y * ms[wave][t1];
        float a2 = v.z * ms[wave][t2], a3 = v.w * ms[wave][t3];
        sx += a0*v.x + a1*v.y + a2*v.z + a3*v.w;          // f32 sum m*x^2
        int c = i >> 1;
        int s = (c & ~7) | ((c ^ rk) & 7);                // XOR swizzle (16B chunks)
        ushort4 w; w.x = f2bf(a0); w.y = f2bf(a1); w.z = f2bf(a2); w.w = f2bf(a3);
        *(ushort4*)(arow + s * 8 + (i & 1) * 4) = w;
    }
    // extension k in [4060,4466): mask values (bf16-exact 0/1); [4466,4480): zero pad
    for (int i = 1015 + lane; i < 1120; i += 64) {
        int k = 4 * i;
        ushort4 w;
        w.x = (k     < KE_) ? f2bf(ms[wave][k     - K0_]) : (ushort_t)0;
        w.y = (k + 1 < KE_) ? f2bf(ms[wave][k + 1 - K0_]) : (ushort_t)0;
        w.z = (k + 2 < KE_) ? f2bf(ms[wave][k + 2 - K0_]) : (ushort_t)0;
        w.w = (k + 3 < KE_) ? f2bf(ms[wave][k + 3 - K0_]) : (ushort_t)0;
        int c = i >> 1;
        int s = (c & ~7) | ((c ^ rk) & 7);
        *(ushort4*)(arow + s * 8 + (i & 1) * 4) = w;
    }
#pragma unroll
    for (int off = 32; off >= 1; off >>= 1) sx += __shfl_xor(sx, off, 64);
    if (lane == 0) sq_x[row] = sx;
}

// ---------------- k2: bf16 MFMA GEMM, BM=64 BN=64 BK=128, K split 8-way -----------
// grid 1024: mb = blk>>3 (M tile, 128 tiles), ks = blk&7 (chunks 5,5,5,4,4,4,4,4).
// BM 128->64: 4 blocks/CU resident (was 2) to hide the DMA/barrier latency; LDS
// halves to 32KB; numerics bit-identical (same fragment sequence per output).
__global__ __launch_bounds__(256) void k2_gemm(
    const ushort_t* __restrict__ axb, const ushort_t* __restrict__ bxb,
    float* __restrict__ partial)
{
    __shared__ ushort_t As[64 * 128];    // 16KB, rows packed 256B, pre-swizzled
    __shared__ ushort_t Bs[64 * 128];    // 16KB
    const int tid = threadIdx.x, wave = tid >> 6, lane = tid & 63;
    const int mb = blockIdx.x >> 3, ks = blockIdx.x & 7;
    const int rowBase = mb * 64;         // 64-aligned -> global row&7 == local row&7
    const int cstart = ks * 4 + (ks < 3 ? ks : 3);
    const int ccnt = (ks < 3) ? 5 : 4;
    const int mh = (wave & 1) * 32;      // wave M offset (2x2 wave grid)
    const int nh = (wave >> 1) * 32;     // wave N offset
    const int m16 = lane & 15, q4 = lane >> 4;
    const int srow4 = lane >> 4, scol = lane & 15;   // staging lane split

    f32x4 acc[2][2];
#pragma unroll
    for (int a = 0; a < 2; a++)
#pragma unroll
        for (int bb = 0; bb < 2; bb++) acc[a][bb] = (f32x4)0.f;

    for (int cc = 0; cc < ccnt; cc++) {
        const int ch = cstart + cc;
        __syncthreads();                 // previous tile consumed
        // A: wave stages rows [wave*16, wave*16+16): 4 gl_lds16 (4 rows x 256B each)
#pragma unroll
        for (int j = 0; j < 4; j++) {
            int r = wave * 16 + j * 4 + srow4;
            const ushort_t* g = axb + (size_t)(rowBase + r) * KP_ + (ch * 16 + scol) * 8;
            gl_lds16(g, &As[(wave * 16 + j * 4) * 128]);
        }
        // B: wave stages rows [wave*16, wave*16+16)
#pragma unroll
        for (int j = 0; j < 4; j++) {
            int r = wave * 16 + j * 4 + srow4;
            const ushort_t* g = bxb + (size_t)r * KP_ + (ch * 16 + scol) * 8;
            gl_lds16(g, &Bs[(wave * 16 + j * 4) * 128]);
        }
        __syncthreads();                 // staged tile visible
#pragma unroll
        for (int k4 = 0; k4 < 4; k4++) {
            const int chk = k4 * 4 + q4;                 // logical 16B chunk in tile
            const int sw = (chk & ~7) | ((chk ^ m16) & 7); // XOR unswizzle (row&7 = m16&7)
            bf16x8 af[2], bfr[2];
#pragma unroll
            for (int mt = 0; mt < 2; mt++)
                af[mt] = *(const bf16x8*)&As[(mh + mt * 16 + m16) * 128 + sw * 8];
#pragma unroll
            for (int nt = 0; nt < 2; nt++)
                bfr[nt] = *(const bf16x8*)&Bs[(nh + nt * 16 + m16) * 128 + sw * 8];
#pragma unroll
            for (int mt = 0; mt < 2; mt++)
#pragma unroll
                for (int nt = 0; nt < 2; nt++)
                    acc[mt][nt] = __builtin_amdgcn_mfma_f32_16x16x32_bf16(
                        af[mt], bfr[nt], acc[mt][nt], 0, 0, 0);
        }
    }
    // epilogue: C/D layout col(n)=lane&15, row(m)=(lane>>4)*4+reg  [m89-verified]
#pragma unroll
    for (int mt = 0; mt < 2; mt++)
#pragma unroll
        for (int nt = 0; nt < 2; nt++)
#pragma unroll
            for (int q = 0; q < 4; q++) {
                int gr = rowBase + mh + mt * 16 + q4 * 4 + q;
                int gp = nh + nt * 16 + m16;
                partial[((size_t)ks * B_ + gr) * P_ + gp] = acc[mt][nt][q];
            }
}

// ---------------- k3: reduce partials + sq_x, argmin, gather, scalars --------------
__global__ __launch_bounds__(256) void k3_fin(
    const float* __restrict__ partial, const float* __restrict__ sq_x,
    const float* __restrict__ protos, const int* __restrict__ label,
    float* __restrict__ out)
{
    __shared__ int sidx[4];
    const int tid = threadIdx.x, wave = tid >> 6, lane = tid & 63;
    const int b = blockIdx.x * 4 + wave;
    float v = sq_x[b];
#pragma unroll
    for (int ks = 0; ks < NKS_; ks++)
        v += partial[((size_t)ks * B_ + b) * P_ + lane];
    out[OUT_DIST + (size_t)b * 64 + lane] = v;

    float bv = v; int bi = lane;
#pragma unroll
    for (int off = 32; off >= 1; off >>= 1) {
        float ov = __shfl_xor(bv, off, 64);
        int   oi = __shfl_xor(bi, off, 64);
        if (ov < bv || (ov == bv && oi < bi)) { bv = ov; bi = oi; }
    }
    if (lane == 0) {
        sidx[wave] = bi;
        out[OUT_IDX + b] = (float)bi;
        out[OUT_LAB + b] = (float)label[b];
    }
    __syncthreads();
#pragma unroll
    for (int w2 = 0; w2 < 4; w2++) {
        const int bb = blockIdx.x * 4 + w2;
        const float* src = protos + (size_t)sidx[w2] * (T_ * D_);
        float* dst = out + OUT_SEQ + (size_t)bb * (T_ * D_);
        for (int i = tid; i < 1015; i += 256)
            *(float4*)(dst + 4 * i) = *(const float4*)(src + 4 * i);
    }
}

extern "C" void kernel_launch(void* const* d_in, const int* in_sizes, int n_in,
                              void* d_out, int out_size, void* d_ws, size_t ws_size,
                              hipStream_t stream) {
    const float* x      = (const float*)d_in[0];
    const int*   label  = (const int*)d_in[1];
    const float* mask   = (const float*)d_in[2];
    const float* protos = (const float*)d_in[3];
    float* out = (float*)d_out;
    char*  ws  = (char*)d_ws;

    ushort_t* bxb     = (ushort_t*)(ws);            // 64*4480*2 = 573440 B
    float*    sq_x    = (float*)(ws + 573440);      // 32 KB
    float*    partial = (float*)(ws + 606208);      // 8*8192*64*4 = 16.8 MB
    // A-blob scratch lives in the out_seq region (73.4MB < 133MB); k3 overwrites it
    ushort_t* axb     = (ushort_t*)(out + OUT_SEQ);

    hipLaunchKernelGGL(k0_prep, dim3(2112), dim3(256), 0, stream,
                       x, mask, protos, axb, bxb, out + OUT_IN, out + OUT_MASK, sq_x);
    hipLaunchKernelGGL(k2_gemm, dim3(1024), dim3(256), 0, stream, axb, bxb, partial);
    hipLaunchKernelGGL(k3_fin, dim3(B_ / 4), dim3(256), 0, stream,
                       partial, sq_x, protos, label, out);
}